// Round 1
// baseline (666.094 us; speedup 1.0000x reference)
//
#include <hip/hip_runtime.h>

#define NNODES 50000
#define NEDGES 800000
#define NG 50
#define PI_OVER_CUT 0.31415926535897931f
#define LN2 0.69314718055994531f

static_assert(NEDGES % 64 == 0, "edge tiling assumes E % 64 == 0");

typedef float f32x4 __attribute__((ext_vector_type(4)));
typedef short s16x8 __attribute__((ext_vector_type(8)));

static __device__ __forceinline__ short f2bf(float f) {
  union { float f; unsigned u; } v; v.f = f;
  return (short)((v.u + 0x7fffu + ((v.u >> 16) & 1u)) >> 16);  // RNE
}

// softplus(x) - ln2, numerically stable
static __device__ __forceinline__ float sp_shift(float x) {
  return fmaxf(x, 0.f) + __logf(1.f + __expf(-fabsf(x))) - LN2;
}

// ---------------- K1: h1 = X @ W^T  (fp32, [N,128]x[128,128]) ----------------
__global__ __launch_bounds__(256) void cfconv_lin1(const float* __restrict__ X,
                                                   const float* __restrict__ W,
                                                   float* __restrict__ Y) {
  __shared__ __align__(16) float wT[128 * 68];   // wT[k][c] = W[c0+c][k], pad 68
  __shared__ __align__(16) float xs[64 * 132];   // xs[r][k], pad 132
  const int tid = threadIdx.x;
  const int row0 = (blockIdx.x >> 1) * 64;
  const int c0 = (blockIdx.x & 1) * 64;
  for (int i = tid; i < 64 * 128; i += 256) {
    int c = i >> 7, k = i & 127;
    wT[k * 68 + c] = W[(c0 + c) * 128 + k];
  }
  for (int i = tid; i < 64 * 128; i += 256) {
    int r = i >> 7, k = i & 127;
    int row = row0 + r;
    xs[r * 132 + k] = (row < NNODES) ? X[row * 128 + k] : 0.f;
  }
  __syncthreads();
  const int c4 = (tid & 15) * 4;
  const int r4 = (tid >> 4) * 4;
  f32x4 a0 = {}, a1 = {}, a2 = {}, a3 = {};
#pragma unroll 4
  for (int k = 0; k < 128; ++k) {
    f32x4 wv = *(const f32x4*)&wT[k * 68 + c4];
    a0 += wv * xs[(r4 + 0) * 132 + k];
    a1 += wv * xs[(r4 + 1) * 132 + k];
    a2 += wv * xs[(r4 + 2) * 132 + k];
    a3 += wv * xs[(r4 + 3) * 132 + k];
  }
  const int row = row0 + r4;
  if (row + 0 < NNODES) *(f32x4*)&Y[(row + 0) * 128 + c0 + c4] = a0;
  if (row + 1 < NNODES) *(f32x4*)&Y[(row + 1) * 128 + c0 + c4] = a1;
  if (row + 2 < NNODES) *(f32x4*)&Y[(row + 2) * 128 + c0 + c4] = a2;
  if (row + 3 < NNODES) *(f32x4*)&Y[(row + 3) * 128 + c0 + c4] = a3;
}

// ---------------- K3: out = (h1 + agg) @ W^T + b, in place on agg ------------
__global__ __launch_bounds__(256) void cfconv_lin2(const float* __restrict__ H1,
                                                   float* AO,  // agg in / out
                                                   const float* __restrict__ W,
                                                   const float* __restrict__ Bias) {
  __shared__ __align__(16) float wT[128 * 68];
  __shared__ __align__(16) float xs[64 * 132];
  const int tid = threadIdx.x;
  const int row0 = (blockIdx.x >> 1) * 64;
  const int c0 = (blockIdx.x & 1) * 64;
  for (int i = tid; i < 64 * 128; i += 256) {
    int c = i >> 7, k = i & 127;
    wT[k * 68 + c] = W[(c0 + c) * 128 + k];
  }
  for (int i = tid; i < 64 * 128; i += 256) {
    int r = i >> 7, k = i & 127;
    int row = row0 + r;
    xs[r * 132 + k] = (row < NNODES) ? (H1[row * 128 + k] + AO[row * 128 + k]) : 0.f;
  }
  __syncthreads();
  const int c4 = (tid & 15) * 4;
  const int r4 = (tid >> 4) * 4;
  f32x4 a0 = {}, a1 = {}, a2 = {}, a3 = {};
#pragma unroll 4
  for (int k = 0; k < 128; ++k) {
    f32x4 wv = *(const f32x4*)&wT[k * 68 + c4];
    a0 += wv * xs[(r4 + 0) * 132 + k];
    a1 += wv * xs[(r4 + 1) * 132 + k];
    a2 += wv * xs[(r4 + 2) * 132 + k];
    a3 += wv * xs[(r4 + 3) * 132 + k];
  }
  const f32x4 bv = *(const f32x4*)&Bias[c0 + c4];
  a0 += bv; a1 += bv; a2 += bv; a3 += bv;
  const int row = row0 + r4;
  if (row + 0 < NNODES) *(f32x4*)&AO[(row + 0) * 128 + c0 + c4] = a0;
  if (row + 1 < NNODES) *(f32x4*)&AO[(row + 1) * 128 + c0 + c4] = a1;
  if (row + 2 < NNODES) *(f32x4*)&AO[(row + 2) * 128 + c0 + c4] = a2;
  if (row + 3 < NNODES) *(f32x4*)&AO[(row + 3) * 128 + c0 + c4] = a3;
}

// ---------------- K2: fused per-edge filter MLP + gather + scatter -----------
// block = 256 threads = 4 waves, 64 edges per tile (16 per wave), persistent.
__global__ __launch_bounds__(256) void cfconv_edge(
    const int* __restrict__ ei, const float* __restrict__ ew,
    const float* __restrict__ attr,
    const float* __restrict__ w1, const float* __restrict__ b1,
    const float* __restrict__ w2, const float* __restrict__ b2,
    const float* __restrict__ h1, float* agg) {
  __shared__ __align__(16) short sB1[8192];    // W1^T frags: [s<2][t<8][lane][8]
  __shared__ __align__(16) short sB2[16384];   // W2^T frags: [s<4][t<8][lane][8]
  __shared__ __align__(16) short sA[4096];     // attr tile [64e][64g] bf16, swizzled
  __shared__ __align__(16) short sX[8192];     // per-wave X tile [16][128] bf16, swizzled
  __shared__ float sb1[128], sb2[128];
  const int tid = threadIdx.x;
  if (tid < 128) { sb1[tid] = b1[tid]; sb2[tid] = b2[tid]; }
  // B-operand fragment layout: lane l holds B[k=(l>>4)*8+j][n=(l&15)]
  for (int i = tid; i < 8192; i += 256) {
    int j = i & 7, l = (i >> 3) & 63, t = (i >> 9) & 7, s = i >> 12;
    int g = s * 32 + (l >> 4) * 8 + j;
    int f = t * 16 + (l & 15);
    sB1[i] = f2bf(g < NG ? w1[f * NG + g] : 0.f);
  }
  for (int i = tid; i < 16384; i += 256) {
    int j = i & 7, l = (i >> 3) & 63, t = (i >> 9) & 7, s = (i >> 12) & 3;
    int k = s * 32 + (l >> 4) * 8 + j;
    int f = t * 16 + (l & 15);
    sB2[i] = f2bf(w2[f * 128 + k]);
  }
  const int lane = tid & 63;
  const int wave = tid >> 6;
  const int lrow = lane & 15;
  const int lk = lane >> 4;
  const s16x8* B1 = (const s16x8*)sB1;
  const s16x8* B2 = (const s16x8*)sB2;
  char* sXw = (char*)(sX + wave * 2048);
  const int ntiles = NEDGES / 64;
  for (int tile = blockIdx.x; tile < ntiles; tile += gridDim.x) {
    const int e0 = tile * 64;
    __syncthreads();  // previous iteration done with sA
    for (int i = tid; i < 4096; i += 256) {
      int e = i >> 6, g = i & 63;
      float v = (g < NG) ? attr[(e0 + e) * NG + g] : 0.f;
      int a = (e * 128 + g * 2) ^ ((e & 7) << 4);
      *(short*)((char*)sA + a) = f2bf(v);
    }
    __syncthreads();
    // ---- stage 1: X = attr @ W1^T ----
    f32x4 acc[8] = {};
#pragma unroll
    for (int s = 0; s < 2; ++s) {
      int ab = ((wave * 16 + lrow) * 128 + s * 64 + lk * 16) ^ ((lrow & 7) << 4);
      s16x8 av = *(const s16x8*)((const char*)sA + ab);
#pragma unroll
      for (int t = 0; t < 8; ++t)
        acc[t] = __builtin_amdgcn_mfma_f32_16x16x32_bf16(av, B1[(s * 8 + t) * 64 + lane], acc[t], 0, 0, 0);
    }
    // softplus, write wave-private X tile (bf16, swizzled). Same-wave LDS -> no barrier.
#pragma unroll
    for (int t = 0; t < 8; ++t) {
      int f = t * 16 + lrow;
      float bb = sb1[f];
#pragma unroll
      for (int r = 0; r < 4; ++r) {
        int row = lk * 4 + r;
        float v = sp_shift(acc[t][r] + bb);
        int a = (row * 256 + f * 2) ^ ((row & 7) << 4);
        *(short*)(sXw + a) = f2bf(v);
      }
    }
    // ---- stage 2: S = X @ W2^T ----
    f32x4 acc2[8] = {};
#pragma unroll
    for (int s = 0; s < 4; ++s) {
      int ab = (lrow * 256 + s * 64 + lk * 16) ^ ((lrow & 7) << 4);
      s16x8 av = *(const s16x8*)(sXw + ab);
#pragma unroll
      for (int t = 0; t < 8; ++t)
        acc2[t] = __builtin_amdgcn_mfma_f32_16x16x32_bf16(av, B2[(s * 8 + t) * 64 + lane], acc2[t], 0, 0, 0);
    }
    // ---- epilogue: W = (softplus(S)-ln2)*c ; msg = W * h1[src]; scatter to dst
    const int ebase = e0 + wave * 16 + lk * 4;
    int dst[4], src[4];
    float cw[4];
#pragma unroll
    for (int r = 0; r < 4; ++r) {
      int e = ebase + r;
      dst[r] = ei[e];
      src[r] = ei[NEDGES + e];
      cw[r] = 0.5f * (__cosf(ew[e] * PI_OVER_CUT) + 1.f);
    }
#pragma unroll
    for (int t = 0; t < 8; ++t) {
      int f = t * 16 + lrow;
      float bb = sb2[f];
#pragma unroll
      for (int r = 0; r < 4; ++r) {
        float Wv = sp_shift(acc2[t][r] + bb) * cw[r];
        float m = Wv * h1[src[r] * 128 + f];
        atomicAdd(&agg[dst[r] * 128 + f], m);
      }
    }
  }
}

extern "C" void kernel_launch(void* const* d_in, const int* in_sizes, int n_in,
                              void* d_out, int out_size, void* d_ws, size_t ws_size,
                              hipStream_t stream) {
  const float* h      = (const float*)d_in[0];
  const int*   ei     = (const int*)d_in[1];
  const float* ew     = (const float*)d_in[2];
  const float* attr   = (const float*)d_in[3];
  const float* lin1_w = (const float*)d_in[4];
  const float* nn_w1  = (const float*)d_in[5];
  const float* nn_b1  = (const float*)d_in[6];
  const float* nn_w2  = (const float*)d_in[7];
  const float* nn_b2  = (const float*)d_in[8];
  const float* lin2_w = (const float*)d_in[9];
  const float* lin2_b = (const float*)d_in[10];
  float* out = (float*)d_out;   // doubles as the agg accumulator
  float* h1  = (float*)d_ws;    // [NNODES*128] fp32 scratch

  hipMemsetAsync(out, 0, (size_t)NNODES * 128 * sizeof(float), stream);
  const int rb2 = ((NNODES + 63) / 64) * 2;
  cfconv_lin1<<<rb2, 256, 0, stream>>>(h, lin1_w, h1);
  cfconv_edge<<<1024, 256, 0, stream>>>(ei, ew, attr, nn_w1, nn_b1, nn_w2, nn_b2, h1, out);
  cfconv_lin2<<<rb2, 256, 0, stream>>>(h1, out, lin2_w, lin2_b);
}

// Round 2
// 572.709 us; speedup vs baseline: 1.1631x; 1.1631x over previous
//
#include <hip/hip_runtime.h>

#define NNODES 50000
#define NEDGES 800000
#define NG 50
#define PI_OVER_CUT 0.31415926535897931f
#define LN2 0.69314718055994531f

static_assert(NEDGES % 64 == 0, "edge tiling assumes E % 64 == 0");

typedef float f32x4 __attribute__((ext_vector_type(4)));
typedef float f32x2 __attribute__((ext_vector_type(2)));
typedef short s16x8 __attribute__((ext_vector_type(8)));

static __device__ __forceinline__ short f2bf(float f) {
  union { float f; unsigned u; } v; v.f = f;
  return (short)((v.u + 0x7fffu + ((v.u >> 16) & 1u)) >> 16);  // RNE
}

// softplus(x) - ln2, numerically stable
static __device__ __forceinline__ float sp_shift(float x) {
  return fmaxf(x, 0.f) + __logf(1.f + __expf(-fabsf(x))) - LN2;
}

// ---------------- K1: h1 = X @ W^T  (fp32, [N,128]x[128,128]) ----------------
__global__ __launch_bounds__(256) void cfconv_lin1(const float* __restrict__ X,
                                                   const float* __restrict__ W,
                                                   float* __restrict__ Y) {
  __shared__ __align__(16) float wT[128 * 68];   // wT[k][c] = W[c0+c][k], pad 68
  __shared__ __align__(16) float xs[64 * 132];   // xs[r][k], pad 132
  const int tid = threadIdx.x;
  const int row0 = (blockIdx.x >> 1) * 64;
  const int c0 = (blockIdx.x & 1) * 64;
  for (int i = tid; i < 64 * 128; i += 256) {
    int c = i >> 7, k = i & 127;
    wT[k * 68 + c] = W[(c0 + c) * 128 + k];
  }
  for (int i = tid; i < 64 * 128; i += 256) {
    int r = i >> 7, k = i & 127;
    int row = row0 + r;
    xs[r * 132 + k] = (row < NNODES) ? X[row * 128 + k] : 0.f;
  }
  __syncthreads();
  const int c4 = (tid & 15) * 4;
  const int r4 = (tid >> 4) * 4;
  f32x4 a0 = {}, a1 = {}, a2 = {}, a3 = {};
#pragma unroll 4
  for (int k = 0; k < 128; ++k) {
    f32x4 wv = *(const f32x4*)&wT[k * 68 + c4];
    a0 += wv * xs[(r4 + 0) * 132 + k];
    a1 += wv * xs[(r4 + 1) * 132 + k];
    a2 += wv * xs[(r4 + 2) * 132 + k];
    a3 += wv * xs[(r4 + 3) * 132 + k];
  }
  const int row = row0 + r4;
  if (row + 0 < NNODES) *(f32x4*)&Y[(row + 0) * 128 + c0 + c4] = a0;
  if (row + 1 < NNODES) *(f32x4*)&Y[(row + 1) * 128 + c0 + c4] = a1;
  if (row + 2 < NNODES) *(f32x4*)&Y[(row + 2) * 128 + c0 + c4] = a2;
  if (row + 3 < NNODES) *(f32x4*)&Y[(row + 3) * 128 + c0 + c4] = a3;
}

// ---------------- K3: out = (h1 + agg) @ W^T + b, in place on agg ------------
__global__ __launch_bounds__(256) void cfconv_lin2(const float* __restrict__ H1,
                                                   float* AO,  // agg in / out
                                                   const float* __restrict__ W,
                                                   const float* __restrict__ Bias) {
  __shared__ __align__(16) float wT[128 * 68];
  __shared__ __align__(16) float xs[64 * 132];
  const int tid = threadIdx.x;
  const int row0 = (blockIdx.x >> 1) * 64;
  const int c0 = (blockIdx.x & 1) * 64;
  for (int i = tid; i < 64 * 128; i += 256) {
    int c = i >> 7, k = i & 127;
    wT[k * 68 + c] = W[(c0 + c) * 128 + k];
  }
  for (int i = tid; i < 64 * 128; i += 256) {
    int r = i >> 7, k = i & 127;
    int row = row0 + r;
    xs[r * 132 + k] = (row < NNODES) ? (H1[row * 128 + k] + AO[row * 128 + k]) : 0.f;
  }
  __syncthreads();
  const int c4 = (tid & 15) * 4;
  const int r4 = (tid >> 4) * 4;
  f32x4 a0 = {}, a1 = {}, a2 = {}, a3 = {};
#pragma unroll 4
  for (int k = 0; k < 128; ++k) {
    f32x4 wv = *(const f32x4*)&wT[k * 68 + c4];
    a0 += wv * xs[(r4 + 0) * 132 + k];
    a1 += wv * xs[(r4 + 1) * 132 + k];
    a2 += wv * xs[(r4 + 2) * 132 + k];
    a3 += wv * xs[(r4 + 3) * 132 + k];
  }
  const f32x4 bv = *(const f32x4*)&Bias[c0 + c4];
  a0 += bv; a1 += bv; a2 += bv; a3 += bv;
  const int row = row0 + r4;
  if (row + 0 < NNODES) *(f32x4*)&AO[(row + 0) * 128 + c0 + c4] = a0;
  if (row + 1 < NNODES) *(f32x4*)&AO[(row + 1) * 128 + c0 + c4] = a1;
  if (row + 2 < NNODES) *(f32x4*)&AO[(row + 2) * 128 + c0 + c4] = a2;
  if (row + 3 < NNODES) *(f32x4*)&AO[(row + 3) * 128 + c0 + c4] = a3;
}

// ---------------- K2: fused per-edge filter MLP + gather + scatter -----------
// block = 256 threads = 4 INDEPENDENT waves, each owning 16 edges per tile.
// No barriers in the main loop -> no vmcnt(0) drain of atomics per tile.
__global__ __launch_bounds__(256) void cfconv_edge(
    const int* __restrict__ ei, const float* __restrict__ ew,
    const float* __restrict__ attr,
    const float* __restrict__ w1, const float* __restrict__ b1,
    const float* __restrict__ w2, const float* __restrict__ b2,
    const float* __restrict__ h1, float* __restrict__ agg) {
  __shared__ __align__(16) short sB1[8192];    // W1^T frags: [s<2][t<8][lane][8]
  __shared__ __align__(16) short sB2[16384];   // W2^T frags: [s<4][t<8][lane][8]
  __shared__ __align__(16) short sA[4][1024];  // per-wave attr tile [16e][64g] bf16, swizzled
  __shared__ __align__(16) short sX[4][2048];  // per-wave X tile [16][128] bf16, swizzled
  __shared__ float sb1[128], sb2[128];
  const int tid = threadIdx.x;
  if (tid < 128) { sb1[tid] = b1[tid]; sb2[tid] = b2[tid]; }
  // B-operand fragment layout: lane l holds B[k=(l>>4)*8+j][n=(l&15)]
  for (int i = tid; i < 8192; i += 256) {
    int j = i & 7, l = (i >> 3) & 63, t = (i >> 9) & 7, s = i >> 12;
    int g = s * 32 + (l >> 4) * 8 + j;
    int f = t * 16 + (l & 15);
    sB1[i] = f2bf(g < NG ? w1[f * NG + g] : 0.f);
  }
  for (int i = tid; i < 16384; i += 256) {
    int j = i & 7, l = (i >> 3) & 63, t = (i >> 9) & 7, s = (i >> 12) & 3;
    int k = s * 32 + (l >> 4) * 8 + j;
    int f = t * 16 + (l & 15);
    sB2[i] = f2bf(w2[f * 128 + k]);
  }
  __syncthreads();   // weights ready; read-only from here on
  const int lane = tid & 63;
  const int wave = tid >> 6;
  const int lrow = lane & 15;
  const int lk = lane >> 4;
  const s16x8* B1 = (const s16x8*)sB1;
  const s16x8* B2 = (const s16x8*)sB2;
  char* sAw = (char*)sA[wave];
  char* sXw = (char*)sX[wave];
  const int nwt = NEDGES / 16;               // 16-edge wave-tiles
  const int gw0 = blockIdx.x * 4 + wave;     // global wave id
  const int gstride = gridDim.x * 4;
  for (int wt = gw0; wt < nwt; wt += gstride) {
    const int e0 = wt * 16;
    // ---- indices, cutoff, and h1 gathers issued FIRST (hide under MFMA) ----
    int dst[4], src[4];
    float cw[4];
#pragma unroll
    for (int r = 0; r < 4; ++r) {
      int e = e0 + lk * 4 + r;
      dst[r] = ei[e];
      src[r] = ei[NEDGES + e];
      cw[r] = 0.5f * (__cosf(ew[e] * PI_OVER_CUT) + 1.f);
    }
    float hv[8][4];
#pragma unroll
    for (int t = 0; t < 8; ++t)
#pragma unroll
      for (int r = 0; r < 4; ++r)
        hv[t][r] = h1[(size_t)src[r] * 128 + t * 16 + lrow];
    // ---- stage this wave's 16x50 attr rows (contiguous) into sAw as bf16 ---
    const float* arow = attr + (size_t)e0 * NG;
#pragma unroll
    for (int u = lane; u < 512; u += 64) {   // 512 bf16-pairs = 16x64 (pad g>=50)
      int e = u >> 5, gp = u & 31;
      f32x2 v = {0.f, 0.f};
      if (gp < 25) v = *(const f32x2*)(arow + e * NG + gp * 2);
      unsigned pk = (unsigned short)f2bf(v.x) | ((unsigned)(unsigned short)f2bf(v.y) << 16);
      int a = (e * 128 + gp * 4) ^ ((e & 7) << 4);
      *(unsigned*)(sAw + a) = pk;
    }
    // same-wave LDS write->read: compiler inserts lgkmcnt waits, no barrier needed
    // ---- stage 1: X = attr @ W1^T ----
    f32x4 acc[8] = {};
#pragma unroll
    for (int s = 0; s < 2; ++s) {
      int ab = (lrow * 128 + s * 64 + lk * 16) ^ ((lrow & 7) << 4);
      s16x8 av = *(const s16x8*)(sAw + ab);
#pragma unroll
      for (int t = 0; t < 8; ++t)
        acc[t] = __builtin_amdgcn_mfma_f32_16x16x32_bf16(av, B1[(s * 8 + t) * 64 + lane], acc[t], 0, 0, 0);
    }
    // softplus, write wave-private X tile (bf16, swizzled)
#pragma unroll
    for (int t = 0; t < 8; ++t) {
      int f = t * 16 + lrow;
      float bb = sb1[f];
#pragma unroll
      for (int r = 0; r < 4; ++r) {
        int row = lk * 4 + r;
        float v = sp_shift(acc[t][r] + bb);
        int a = (row * 256 + f * 2) ^ ((row & 7) << 4);
        *(short*)(sXw + a) = f2bf(v);
      }
    }
    // ---- stage 2: S = X @ W2^T ----
    f32x4 acc2[8] = {};
#pragma unroll
    for (int s = 0; s < 4; ++s) {
      int ab = (lrow * 256 + s * 64 + lk * 16) ^ ((lrow & 7) << 4);
      s16x8 av = *(const s16x8*)(sXw + ab);
#pragma unroll
      for (int t = 0; t < 8; ++t)
        acc2[t] = __builtin_amdgcn_mfma_f32_16x16x32_bf16(av, B2[(s * 8 + t) * 64 + lane], acc2[t], 0, 0, 0);
    }
    // ---- epilogue: W = (softplus(S)-ln2)*c ; msg = W * h1[src]; scatter -----
#pragma unroll
    for (int t = 0; t < 8; ++t) {
      int f = t * 16 + lrow;
      float bb = sb2[f];
#pragma unroll
      for (int r = 0; r < 4; ++r) {
        float Wv = sp_shift(acc2[t][r] + bb) * cw[r];
        atomicAdd(&agg[(size_t)dst[r] * 128 + f], Wv * hv[t][r]);
      }
    }
    // no barrier: atomics drain while next tile stages/computes
  }
}

extern "C" void kernel_launch(void* const* d_in, const int* in_sizes, int n_in,
                              void* d_out, int out_size, void* d_ws, size_t ws_size,
                              hipStream_t stream) {
  const float* h      = (const float*)d_in[0];
  const int*   ei     = (const int*)d_in[1];
  const float* ew     = (const float*)d_in[2];
  const float* attr   = (const float*)d_in[3];
  const float* lin1_w = (const float*)d_in[4];
  const float* nn_w1  = (const float*)d_in[5];
  const float* nn_b1  = (const float*)d_in[6];
  const float* nn_w2  = (const float*)d_in[7];
  const float* nn_b2  = (const float*)d_in[8];
  const float* lin2_w = (const float*)d_in[9];
  const float* lin2_b = (const float*)d_in[10];
  float* out = (float*)d_out;   // doubles as the agg accumulator
  float* h1  = (float*)d_ws;    // [NNODES*128] fp32 scratch

  hipMemsetAsync(out, 0, (size_t)NNODES * 128 * sizeof(float), stream);
  const int rb2 = ((NNODES + 63) / 64) * 2;
  cfconv_lin1<<<rb2, 256, 0, stream>>>(h, lin1_w, h1);
  cfconv_edge<<<512, 256, 0, stream>>>(ei, ew, attr, nn_w1, nn_b1, nn_w2, nn_b2, h1, out);
  cfconv_lin2<<<rb2, 256, 0, stream>>>(h1, out, lin2_w, lin2_b);
}